// Round 9
// baseline (4545.058 us; speedup 1.0000x reference)
//
#include <hip/hip_runtime.h>
#include <hip/hip_bf16.h>
#include <cstdio>

// GCNTox21 — round 9. conv_k VALU diet: packed f16 v_dot2 for the 16-dim
// e16·Wae dot (8 dot2/channel vs 16 unpack + 16 fma), 2-edge unrolled loop
// (independent loads, no register rotation), Wb matvec reads global (L1)
// instead of a 32KB LDS tile. Round-8 counters: VGPR 124/occ 18%/VALU 32%.

#define N_NODES 100000
#define N_EDGES 1600000
#define NUM_GRAPHS 4096

typedef unsigned short u16;
typedef unsigned int u32;
typedef _Float16 h2 __attribute__((ext_vector_type(2)));

#if defined(__has_builtin)
#if __has_builtin(__builtin_amdgcn_fdot2)
#define DOT2(a, b, c) __builtin_amdgcn_fdot2((a), (b), (c), false)
#endif
#endif
#ifndef DOT2
#define DOT2(a, b, c) ((c) + (float)(a).x * (float)(b).x + (float)(a).y * (float)(b).y)
#endif

__device__ __forceinline__ float b2f(u16 u) { union { u32 i; float f; } c; c.i = ((u32)u) << 16; return c.f; }
__device__ __forceinline__ float b2f_lo(u32 u) { union { u32 i; float f; } c; c.i = u << 16; return c.f; }
__device__ __forceinline__ float b2f_hi(u32 u) { union { u32 i; float f; } c; c.i = u & 0xffff0000u; return c.f; }
__device__ __forceinline__ u16 f2b(float f) {
    __hip_bfloat16 h = __float2bfloat16(f);
    return *reinterpret_cast<u16*>(&h);
}

template <typename ST> __device__ __forceinline__ void st_store(ST* p, float v);
template <> __device__ __forceinline__ void st_store<float>(float* p, float v) { *p = v; }
template <> __device__ __forceinline__ void st_store<u16>(u16* p, float v) { *p = f2b(v); }
template <typename ST> __device__ __forceinline__ float st_load(const ST* p);
template <> __device__ __forceinline__ float st_load<float>(const float* p) { return *p; }
template <> __device__ __forceinline__ float st_load<u16>(const u16* p) { return b2f(*p); }

template <typename ST, int CPL>
__device__ __forceinline__ void ld_row(const ST* base, float out[CPL]) {
    if constexpr (CPL == 1) {
        out[0] = st_load(base);
    } else {
        if constexpr (sizeof(ST) == 4) {
            float2 v = *(const float2*)base;
            out[0] = v.x; out[1] = v.y;
        } else {
            u32 v = *(const u32*)base;
            out[0] = b2f_lo(v); out[1] = b2f_hi(v);
        }
    }
}

// ---------------- CSR build ----------------
__global__ __launch_bounds__(256) void hist_k(const int* __restrict__ dst, int* __restrict__ hist) {
    int e = blockIdx.x * 256 + threadIdx.x;
    if (e < N_EDGES) atomicAdd(&hist[dst[e]], 1);
}

__global__ __launch_bounds__(256) void scan_part_k(const int* __restrict__ hist,
        int* __restrict__ excl, int* __restrict__ bsum) {
    __shared__ int sm[256];
    int t = threadIdx.x, b = blockIdx.x;
    int base = b * 1024 + t * 4;
    int v0 = (base + 0 < N_NODES) ? hist[base + 0] : 0;
    int v1 = (base + 1 < N_NODES) ? hist[base + 1] : 0;
    int v2 = (base + 2 < N_NODES) ? hist[base + 2] : 0;
    int v3 = (base + 3 < N_NODES) ? hist[base + 3] : 0;
    int tsum = v0 + v1 + v2 + v3;
    sm[t] = tsum;
    __syncthreads();
    for (int o = 1; o < 256; o <<= 1) {
        int x = (t >= o) ? sm[t - o] : 0;
        __syncthreads();
        sm[t] += x;
        __syncthreads();
    }
    int texcl = sm[t] - tsum;
    if (base + 0 < N_NODES) excl[base + 0] = texcl;
    if (base + 1 < N_NODES) excl[base + 1] = texcl + v0;
    if (base + 2 < N_NODES) excl[base + 2] = texcl + v0 + v1;
    if (base + 3 < N_NODES) excl[base + 3] = texcl + v0 + v1 + v2;
    if (t == 255) bsum[b] = sm[255];
}

__global__ __launch_bounds__(256) void scan_top_k(int* __restrict__ bsum, int* __restrict__ boff,
        int nb, int* __restrict__ row_ptr_last) {
    __shared__ int sm[256];
    int t = threadIdx.x;
    int v = (t < nb) ? bsum[t] : 0;
    sm[t] = v;
    __syncthreads();
    for (int o = 1; o < 256; o <<= 1) {
        int x = (t >= o) ? sm[t - o] : 0;
        __syncthreads();
        sm[t] += x;
        __syncthreads();
    }
    if (t < nb) boff[t] = sm[t] - v;
    if (t == 0) *row_ptr_last = sm[255];
}

__global__ __launch_bounds__(256) void scan_add_k(int* __restrict__ excl, const int* __restrict__ boff,
        int* __restrict__ row_ptr, int* __restrict__ cursor) {
    int i = blockIdx.x * 256 + threadIdx.x;
    if (i >= N_NODES) return;
    int s = excl[i] + boff[i >> 10];
    row_ptr[i] = s;
    cursor[i] = s;
}

__global__ __launch_bounds__(256) void scatter_k(const int* __restrict__ src, const int* __restrict__ dst,
        int* __restrict__ cursor, int* __restrict__ sorted_eid, int* __restrict__ srcs) {
    int e = blockIdx.x * 256 + threadIdx.x;
    if (e < N_EDGES) {
        int p = atomicAdd(&cursor[dst[e]], 1);
        sorted_eid[p] = e;
        srcs[p] = src[e];
    }
}

// ---------------- embeddings ----------------
// e16s[p][k] = relu(edge_attr[sorted_eid[p]] @ We + be), f16, CSR order
__global__ __launch_bounds__(256) void edge_emb_k(const float* __restrict__ ea,
        const float* __restrict__ We, const float* __restrict__ be,
        const int* __restrict__ sorted_eid, _Float16* __restrict__ e16s) {
    int idx = blockIdx.x * 256 + threadIdx.x;
    if (idx >= N_EDGES * 16) return;
    int p = idx >> 4, k = idx & 15;
    int e = sorted_eid[p];
    float acc = be[k];
#pragma unroll
    for (int j = 0; j < 8; ++j) acc += ea[(size_t)e * 8 + j] * We[j * 16 + k];
    e16s[idx] = (_Float16)fmaxf(acc, 0.f);
}

__global__ __launch_bounds__(256) void node_emb_k(const float* __restrict__ x,
        const float* __restrict__ Wn, const float* __restrict__ bn_, float* __restrict__ h) {
    int idx = blockIdx.x * 256 + threadIdx.x;
    if (idx >= N_NODES * 64) return;
    int v = idx >> 6, c = idx & 63;
    float acc = bn_[c];
    for (int k = 0; k < 32; ++k) acc += x[(size_t)v * 32 + k] * Wn[(size_t)k * 64 + c];
    h[idx] = fmaxf(acc, 0.f);
}

// ---------------- projections ----------------
template <int F, int H, typename ST>
__global__ __launch_bounds__(256) void proj_k(const float* __restrict__ h,
        const float* __restrict__ Wa, const float* __restrict__ ba,
        ST* __restrict__ Pd, ST* __restrict__ Ps) {
    int idx = blockIdx.x * 256 + threadIdx.x;
    if (idx >= N_NODES * H) return;
    int v = idx / H, c = idx % H;
    float ad = ba[c], as = 0.f;
    const float* hr = h + (size_t)v * F;
    for (int k = 0; k < F; ++k) {
        float hk = hr[k];
        ad += hk * Wa[(size_t)k * H + c];
        as += hk * Wa[(size_t)(F + k) * H + c];
    }
    st_store(&Pd[idx], ad);
    st_store(&Ps[idx], as);
}

// ---------------- fused conv: CSR gather + mean + Wb mat-vec ----------------
template <int H, int Fo, typename ST>
__global__ __launch_bounds__(256, 4) void conv_k(
        const int* __restrict__ row_ptr, const int* __restrict__ srcs,
        const _Float16* __restrict__ e16s,
        const ST* __restrict__ Pd, const ST* __restrict__ Ps,
        const float* __restrict__ Wae, const float* __restrict__ Wb,
        const float* __restrict__ bb, float* __restrict__ y) {
    constexpr int SL = (H >= 64) ? 64 : 32;   // lanes per node
    constexpr int NPW = 64 / SL;              // nodes per wave
    constexpr int CPL = H / SL;               // channels per lane (1 or 2)
    constexpr int NPB = 4 * NPW;              // nodes per block per iter
    const int wave = threadIdx.x >> 6, lane = threadIdx.x & 63;
    const int sub = lane / SL;
    const int sl = lane % SL;
    const int c0 = sl * CPL;
    // Wae packed as f16 pairs along k: w2h[k2][j] = (Wae[2k2][c], Wae[2k2+1][c])
    h2 w2h[8][CPL];
#pragma unroll
    for (int k2 = 0; k2 < 8; ++k2)
#pragma unroll
        for (int j = 0; j < CPL; ++j) {
            h2 t;
            t.x = (_Float16)Wae[(2 * k2) * H + c0 + j];
            t.y = (_Float16)Wae[(2 * k2 + 1) * H + c0 + j];
            w2h[k2][j] = t;
        }

    for (int v = blockIdx.x * NPB + wave * NPW + sub; v < N_NODES; v += gridDim.x * NPB) {
        float pd[CPL], acc[CPL];
        ld_row<ST, CPL>(&Pd[(size_t)v * H + c0], pd);
#pragma unroll
        for (int j = 0; j < CPL; ++j) acc[j] = 0.f;
        const int p0 = row_ptr[v], p1 = row_ptr[v + 1];
        const int deg = p1 - p0;

        auto edge = [&](uint4 ra, uint4 rb, const float ps[CPL]) {
            union { u32 u; h2 h; } cv;
            h2 ev[8];
            cv.u = ra.x; ev[0] = cv.h; cv.u = ra.y; ev[1] = cv.h;
            cv.u = ra.z; ev[2] = cv.h; cv.u = ra.w; ev[3] = cv.h;
            cv.u = rb.x; ev[4] = cv.h; cv.u = rb.y; ev[5] = cv.h;
            cv.u = rb.z; ev[6] = cv.h; cv.u = rb.w; ev[7] = cv.h;
            float z[CPL];
#pragma unroll
            for (int j = 0; j < CPL; ++j) z[j] = pd[j] + ps[j];
#pragma unroll
            for (int k2 = 0; k2 < 8; ++k2)
#pragma unroll
                for (int j = 0; j < CPL; ++j) z[j] = DOT2(ev[k2], w2h[k2][j], z[j]);
#pragma unroll
            for (int j = 0; j < CPL; ++j) acc[j] += fmaxf(z[j], 0.f);
        };

        int p = p0;
        for (; p + 1 < p1; p += 2) {
            int s0 = srcs[p], s1 = srcs[p + 1];
            const uint4* e0 = (const uint4*)(e16s + (size_t)p * 16);
            const uint4* e1 = (const uint4*)(e16s + (size_t)(p + 1) * 16);
            uint4 a0 = e0[0], a1 = e0[1];
            uint4 b0 = e1[0], b1 = e1[1];
            float ps0[CPL], ps1[CPL];
            ld_row<ST, CPL>(&Ps[(size_t)s0 * H + c0], ps0);
            ld_row<ST, CPL>(&Ps[(size_t)s1 * H + c0], ps1);
            edge(a0, a1, ps0);
            edge(b0, b1, ps1);
        }
        if (p < p1) {
            int s0 = srcs[p];
            const uint4* e0 = (const uint4*)(e16s + (size_t)p * 16);
            uint4 a0 = e0[0], a1 = e0[1];
            float ps0[CPL];
            ld_row<ST, CPL>(&Ps[(size_t)s0 * H + c0], ps0);
            edge(a0, a1, ps0);
        }

        const float invd = (deg > 0) ? 1.f / (float)deg : 0.f;
        float m[CPL];
#pragma unroll
        for (int j = 0; j < CPL; ++j) m[j] = acc[j] * invd;
        const int co = (sl < Fo) ? sl : 0;
        float yv = 0.f;
#pragma unroll
        for (int k = 0; k < H; ++k)
            yv += __shfl(m[k % CPL], sub * SL + k / CPL) * Wb[k * Fo + co];
        if (sl < Fo)
            y[(size_t)v * Fo + sl] = (deg > 0) ? (yv + bb[sl]) : 0.f;
    }
}

// ---------------- BN stats + normalize ----------------
template <int Fo>
__global__ __launch_bounds__(256) void stats2_k(const float* __restrict__ y, float* __restrict__ stats) {
    __shared__ float sh[2 * Fo];
    for (int i = threadIdx.x; i < 2 * Fo; i += 256) sh[i] = 0.f;
    __syncthreads();
    const int co = threadIdx.x % Fo;
    float s1 = 0.f, s2 = 0.f;
    const long long total = (long long)N_NODES * Fo;
    for (long long i = (long long)blockIdx.x * 256 + threadIdx.x; i < total; i += (long long)gridDim.x * 256) {
        float v = y[i];
        s1 += v; s2 += v * v;
    }
    atomicAdd(&sh[co], s1);
    atomicAdd(&sh[Fo + co], s2);
    __syncthreads();
    if (threadIdx.x < 2 * Fo) atomicAdd(&stats[threadIdx.x], sh[threadIdx.x]);
}

template <int Fo>
__global__ __launch_bounds__(256) void bnrelu_k(float* __restrict__ y,
        const float* __restrict__ stats, const float* __restrict__ g, const float* __restrict__ beta) {
    int idx = blockIdx.x * 256 + threadIdx.x;
    if (idx >= N_NODES * Fo) return;
    int co = idx % Fo;
    const float invN = 1.0f / (float)N_NODES;
    float mu = stats[co] * invN;
    float ex2 = stats[Fo + co] * invN;
    float var = fmaxf(ex2 - mu * mu, 0.f);
    float rs = rsqrtf(var + 1e-5f);
    y[idx] = fmaxf((y[idx] - mu) * rs * g[co] + beta[co], 0.f);
}

// ---------------- pooling & head ----------------
__global__ __launch_bounds__(256) void pool_k(const float* __restrict__ h,
        const int* __restrict__ batch, float* __restrict__ pool, int* __restrict__ gcnt) {
    int idx = blockIdx.x * 256 + threadIdx.x;
    if (idx >= N_NODES * 16) return;
    int v = idx >> 4, c = idx & 15;
    int b = batch[v];
    atomicAdd(&pool[b * 16 + c], h[idx]);
    if (c == 0) atomicAdd(&gcnt[b], 1);
}

__global__ __launch_bounds__(256) void out_k(const float* __restrict__ pool,
        const int* __restrict__ gcnt, const float* __restrict__ Wfc,
        const float* __restrict__ bfc, float* __restrict__ out) {
    int idx = blockIdx.x * 256 + threadIdx.x;
    if (idx >= NUM_GRAPHS * 12) return;
    int g = idx / 12, o = idx % 12;
    int cnt = gcnt[g];
    float inv = 1.0f / (float)(cnt > 0 ? cnt : 1);
    float acc = bfc[o];
#pragma unroll
    for (int k = 0; k < 16; ++k) acc += pool[g * 16 + k] * inv * Wfc[k * 12 + o];
    out[idx] = 1.0f / (1.0f + expf(-acc));
}

template <typename ST>
static void run_pipeline(void* const* d_in, void* d_out, char* base, hipStream_t stream) {
    const size_t N = N_NODES, E = N_EDGES, G = NUM_GRAPHS;
    const float* x = (const float*)d_in[0];
    const float* ea = (const float*)d_in[1];
    const int* ei = (const int*)d_in[2];
    const int* srcv = ei;
    const int* dstv = ei + E;
    const int* batch = (const int*)d_in[3];
    const float* Wn = (const float*)d_in[5];  const float* bn_ = (const float*)d_in[6];
    const float* We = (const float*)d_in[7];  const float* be_ = (const float*)d_in[8];
    const float* W1a = (const float*)d_in[9]; const float* b1a = (const float*)d_in[10];
    const float* W1b = (const float*)d_in[11]; const float* b1b = (const float*)d_in[12];
    const float* W2a = (const float*)d_in[13]; const float* b2a = (const float*)d_in[14];
    const float* W2b = (const float*)d_in[15]; const float* b2b = (const float*)d_in[16];
    const float* W3a = (const float*)d_in[17]; const float* b3a = (const float*)d_in[18];
    const float* W3b = (const float*)d_in[19]; const float* b3b = (const float*)d_in[20];
    const float* g1 = (const float*)d_in[21]; const float* be1 = (const float*)d_in[22];
    const float* g2 = (const float*)d_in[23]; const float* be2 = (const float*)d_in[24];
    const float* g3 = (const float*)d_in[25]; const float* be3 = (const float*)d_in[26];
    const float* Wfc = (const float*)d_in[27]; const float* bfc = (const float*)d_in[28];

    size_t off = 0;
    auto take = [&](size_t bytes) { size_t o = off; off += (bytes + 255) & ~(size_t)255; return o; };
    int* hist = (int*)(base + take(N * 4));
    int* cursor = (int*)(base + take(N * 4));
    int* row_ptr = (int*)(base + take((N + 1) * 4));
    int* bsum = (int*)(base + take(256 * 4));
    int* boff = (int*)(base + take(256 * 4));
    int* sorted = (int*)(base + take(E * 4));
    int* srcs = (int*)(base + take(E * 4));
    float* hbuf = (float*)(base + take(N * 64 * 4));
    ST* Pd = (ST*)(base + take(N * 128 * sizeof(ST)));
    ST* Ps = (ST*)(base + take(N * 128 * sizeof(ST)));
    _Float16* e16s = (_Float16*)(base + take(E * 16 * 2));
    float* stats = (float*)(base + take(256 * 4));
    float* pool = (float*)(base + take(G * 16 * 4));
    int* gcnt = (int*)(base + take(G * 4));

    const int NB = (N_NODES + 1023) / 1024;

    // CSR build (+ srcs in sorted order)
    hipMemsetAsync(hist, 0, N * 4, stream);
    hist_k<<<dim3((E + 255) / 256), dim3(256), 0, stream>>>(dstv, hist);
    scan_part_k<<<dim3(NB), dim3(256), 0, stream>>>(hist, cursor, bsum);
    scan_top_k<<<dim3(1), dim3(256), 0, stream>>>(bsum, boff, NB, &row_ptr[N_NODES]);
    scan_add_k<<<dim3((N + 255) / 256), dim3(256), 0, stream>>>(cursor, boff, row_ptr, cursor);
    scatter_k<<<dim3((E + 255) / 256), dim3(256), 0, stream>>>(srcv, dstv, cursor, sorted, srcs);

    // embeddings (e16 f16, CSR order)
    edge_emb_k<<<dim3((E * 16 + 255) / 256), dim3(256), 0, stream>>>(ea, We, be_, sorted, e16s);
    node_emb_k<<<dim3((N * 64 + 255) / 256), dim3(256), 0, stream>>>(x, Wn, bn_, hbuf);

    // conv1: F=64, H=128, Fo=64
    proj_k<64, 128, ST><<<dim3((N * 128 + 255) / 256), dim3(256), 0, stream>>>(hbuf, W1a, b1a, Pd, Ps);
    conv_k<128, 64, ST><<<dim3(2048), dim3(256), 0, stream>>>(row_ptr, srcs, e16s, Pd, Ps,
            W1a + 128 * 128, W1b, b1b, hbuf);
    hipMemsetAsync(stats, 0, 256 * 4, stream);
    stats2_k<64><<<dim3(512), dim3(256), 0, stream>>>(hbuf, stats);
    bnrelu_k<64><<<dim3((N * 64 + 255) / 256), dim3(256), 0, stream>>>(hbuf, stats, g1, be1);

    // conv2: F=64, H=64, Fo=32
    proj_k<64, 64, ST><<<dim3((N * 64 + 255) / 256), dim3(256), 0, stream>>>(hbuf, W2a, b2a, Pd, Ps);
    conv_k<64, 32, ST><<<dim3(2048), dim3(256), 0, stream>>>(row_ptr, srcs, e16s, Pd, Ps,
            W2a + 128 * 64, W2b, b2b, hbuf);
    hipMemsetAsync(stats, 0, 256 * 4, stream);
    stats2_k<32><<<dim3(512), dim3(256), 0, stream>>>(hbuf, stats);
    bnrelu_k<32><<<dim3((N * 32 + 255) / 256), dim3(256), 0, stream>>>(hbuf, stats, g2, be2);

    // conv3: F=32, H=32, Fo=16 (2 nodes/wave)
    proj_k<32, 32, ST><<<dim3((N * 32 + 255) / 256), dim3(256), 0, stream>>>(hbuf, W3a, b3a, Pd, Ps);
    conv_k<32, 16, ST><<<dim3(2048), dim3(256), 0, stream>>>(row_ptr, srcs, e16s, Pd, Ps,
            W3a + 64 * 32, W3b, b3b, hbuf);
    hipMemsetAsync(stats, 0, 256 * 4, stream);
    stats2_k<16><<<dim3(512), dim3(256), 0, stream>>>(hbuf, stats);
    bnrelu_k<16><<<dim3((N * 16 + 255) / 256), dim3(256), 0, stream>>>(hbuf, stats, g3, be3);

    // pool + head
    hipMemsetAsync(pool, 0, G * 16 * 4, stream);
    hipMemsetAsync(gcnt, 0, G * 4, stream);
    pool_k<<<dim3((N * 16 + 255) / 256), dim3(256), 0, stream>>>(hbuf, batch, pool, gcnt);
    out_k<<<dim3((G * 12 + 255) / 256), dim3(256), 0, stream>>>(pool, gcnt, Wfc, bfc, (float*)d_out);
}

extern "C" void kernel_launch(void* const* d_in, const int* in_sizes, int n_in,
                              void* d_out, int out_size, void* d_ws, size_t ws_size,
                              hipStream_t stream) {
    const size_t N = N_NODES, E = N_EDGES, G = NUM_GRAPHS;
    auto need = [&](size_t stbytes) {
        size_t o = 0;
        auto take = [&](size_t b) { o += (b + 255) & ~(size_t)255; };
        take(N * 4); take(N * 4); take((N + 1) * 4); take(256 * 4); take(256 * 4);
        take(E * 4); take(E * 4); take(N * 64 * 4);
        take(N * 128 * stbytes); take(N * 128 * stbytes);
        take(E * 16 * 2);
        take(256 * 4); take(G * 16 * 4); take(G * 4);
        return o;
    };
    if (ws_size >= need(4)) {
        run_pipeline<float>(d_in, d_out, (char*)d_ws, stream);   // fp32 staging
    } else if (ws_size >= need(2)) {
        run_pipeline<u16>(d_in, d_out, (char*)d_ws, stream);     // bf16 staging fallback
    } else {
        fprintf(stderr, "kernel_launch: ws too small: need %zu have %zu\n", need(2), ws_size);
    }
}

// Round 10
// 2217.230 us; speedup vs baseline: 2.0499x; 2.0499x over previous
//
#include <hip/hip_runtime.h>
#include <hip/hip_bf16.h>
#include <cstdio>

// GCNTox21 — round 10. r9 post-mortem: removing the LDS Wb tile made the
// epilogue stream 32KB of Wb from global PER NODE (FETCH 431MB -> 4.7GB).
// This round: r9's lean dot2 edge loop (VGPR 64) + r8's LDS Wb epilogue +
// Ps staged bf16 (halves the dominant per-edge row-gather traffic; Pd stays
// fp32 - loaded once per node).

#define N_NODES 100000
#define N_EDGES 1600000
#define NUM_GRAPHS 4096

typedef unsigned short u16;
typedef unsigned int u32;
typedef _Float16 h2 __attribute__((ext_vector_type(2)));

#if defined(__has_builtin)
#if __has_builtin(__builtin_amdgcn_fdot2)
#define DOT2(a, b, c) __builtin_amdgcn_fdot2((a), (b), (c), false)
#endif
#endif
#ifndef DOT2
#define DOT2(a, b, c) ((c) + (float)(a).x * (float)(b).x + (float)(a).y * (float)(b).y)
#endif

__device__ __forceinline__ float b2f(u16 u) { union { u32 i; float f; } c; c.i = ((u32)u) << 16; return c.f; }
__device__ __forceinline__ float b2f_lo(u32 u) { union { u32 i; float f; } c; c.i = u << 16; return c.f; }
__device__ __forceinline__ float b2f_hi(u32 u) { union { u32 i; float f; } c; c.i = u & 0xffff0000u; return c.f; }
__device__ __forceinline__ u16 f2b(float f) {
    __hip_bfloat16 h = __float2bfloat16(f);
    return *reinterpret_cast<u16*>(&h);
}

// load CPL consecutive bf16 values (c0-aligned)
template <int CPL>
__device__ __forceinline__ void ld_bf16(const u16* base, float out[CPL]) {
    if constexpr (CPL == 1) {
        out[0] = b2f(*base);
    } else {
        u32 v = *(const u32*)base;
        out[0] = b2f_lo(v); out[1] = b2f_hi(v);
    }
}
template <int CPL>
__device__ __forceinline__ void ld_f32(const float* base, float out[CPL]) {
    if constexpr (CPL == 1) {
        out[0] = *base;
    } else {
        float2 v = *(const float2*)base;
        out[0] = v.x; out[1] = v.y;
    }
}

// ---------------- CSR build ----------------
__global__ __launch_bounds__(256) void hist_k(const int* __restrict__ dst, int* __restrict__ hist) {
    int e = blockIdx.x * 256 + threadIdx.x;
    if (e < N_EDGES) atomicAdd(&hist[dst[e]], 1);
}

__global__ __launch_bounds__(256) void scan_part_k(const int* __restrict__ hist,
        int* __restrict__ excl, int* __restrict__ bsum) {
    __shared__ int sm[256];
    int t = threadIdx.x, b = blockIdx.x;
    int base = b * 1024 + t * 4;
    int v0 = (base + 0 < N_NODES) ? hist[base + 0] : 0;
    int v1 = (base + 1 < N_NODES) ? hist[base + 1] : 0;
    int v2 = (base + 2 < N_NODES) ? hist[base + 2] : 0;
    int v3 = (base + 3 < N_NODES) ? hist[base + 3] : 0;
    int tsum = v0 + v1 + v2 + v3;
    sm[t] = tsum;
    __syncthreads();
    for (int o = 1; o < 256; o <<= 1) {
        int x = (t >= o) ? sm[t - o] : 0;
        __syncthreads();
        sm[t] += x;
        __syncthreads();
    }
    int texcl = sm[t] - tsum;
    if (base + 0 < N_NODES) excl[base + 0] = texcl;
    if (base + 1 < N_NODES) excl[base + 1] = texcl + v0;
    if (base + 2 < N_NODES) excl[base + 2] = texcl + v0 + v1;
    if (base + 3 < N_NODES) excl[base + 3] = texcl + v0 + v1 + v2;
    if (t == 255) bsum[b] = sm[255];
}

__global__ __launch_bounds__(256) void scan_top_k(int* __restrict__ bsum, int* __restrict__ boff,
        int nb, int* __restrict__ row_ptr_last) {
    __shared__ int sm[256];
    int t = threadIdx.x;
    int v = (t < nb) ? bsum[t] : 0;
    sm[t] = v;
    __syncthreads();
    for (int o = 1; o < 256; o <<= 1) {
        int x = (t >= o) ? sm[t - o] : 0;
        __syncthreads();
        sm[t] += x;
        __syncthreads();
    }
    if (t < nb) boff[t] = sm[t] - v;
    if (t == 0) *row_ptr_last = sm[255];
}

__global__ __launch_bounds__(256) void scan_add_k(int* __restrict__ excl, const int* __restrict__ boff,
        int* __restrict__ row_ptr, int* __restrict__ cursor) {
    int i = blockIdx.x * 256 + threadIdx.x;
    if (i >= N_NODES) return;
    int s = excl[i] + boff[i >> 10];
    row_ptr[i] = s;
    cursor[i] = s;
}

__global__ __launch_bounds__(256) void scatter_k(const int* __restrict__ src, const int* __restrict__ dst,
        int* __restrict__ cursor, int* __restrict__ sorted_eid, int* __restrict__ srcs) {
    int e = blockIdx.x * 256 + threadIdx.x;
    if (e < N_EDGES) {
        int p = atomicAdd(&cursor[dst[e]], 1);
        sorted_eid[p] = e;
        srcs[p] = src[e];
    }
}

// ---------------- embeddings ----------------
__global__ __launch_bounds__(256) void edge_emb_k(const float* __restrict__ ea,
        const float* __restrict__ We, const float* __restrict__ be,
        const int* __restrict__ sorted_eid, _Float16* __restrict__ e16s) {
    int idx = blockIdx.x * 256 + threadIdx.x;
    if (idx >= N_EDGES * 16) return;
    int p = idx >> 4, k = idx & 15;
    int e = sorted_eid[p];
    float acc = be[k];
#pragma unroll
    for (int j = 0; j < 8; ++j) acc += ea[(size_t)e * 8 + j] * We[j * 16 + k];
    e16s[idx] = (_Float16)fmaxf(acc, 0.f);
}

__global__ __launch_bounds__(256) void node_emb_k(const float* __restrict__ x,
        const float* __restrict__ Wn, const float* __restrict__ bn_, float* __restrict__ h) {
    int idx = blockIdx.x * 256 + threadIdx.x;
    if (idx >= N_NODES * 64) return;
    int v = idx >> 6, c = idx & 63;
    float acc = bn_[c];
    for (int k = 0; k < 32; ++k) acc += x[(size_t)v * 32 + k] * Wn[(size_t)k * 64 + c];
    h[idx] = fmaxf(acc, 0.f);
}

// ---------------- projections: Pd fp32, Ps bf16 ----------------
template <int F, int H>
__global__ __launch_bounds__(256) void proj_k(const float* __restrict__ h,
        const float* __restrict__ Wa, const float* __restrict__ ba,
        float* __restrict__ Pd, u16* __restrict__ Ps) {
    int idx = blockIdx.x * 256 + threadIdx.x;
    if (idx >= N_NODES * H) return;
    int v = idx / H, c = idx % H;
    float ad = ba[c], as = 0.f;
    const float* hr = h + (size_t)v * F;
    for (int k = 0; k < F; ++k) {
        float hk = hr[k];
        ad += hk * Wa[(size_t)k * H + c];
        as += hk * Wa[(size_t)(F + k) * H + c];
    }
    Pd[idx] = ad;
    Ps[idx] = f2b(as);
}

// ---------------- fused conv: CSR gather + mean + Wb mat-vec (LDS Wb) ------
template <int H, int Fo>
__global__ __launch_bounds__(256, 4) void conv_k(
        const int* __restrict__ row_ptr, const int* __restrict__ srcs,
        const _Float16* __restrict__ e16s,
        const float* __restrict__ Pd, const u16* __restrict__ Ps,
        const float* __restrict__ Wae, const float* __restrict__ Wb,
        const float* __restrict__ bb, float* __restrict__ y) {
    constexpr int SL = (H >= 64) ? 64 : 32;   // lanes per node
    constexpr int NPW = 64 / SL;              // nodes per wave
    constexpr int CPL = H / SL;               // channels per lane
    constexpr int NPB = 4 * NPW;              // nodes per block per iter
    __shared__ float Wb_sh[H * Fo];
    for (int i = threadIdx.x; i < H * Fo; i += 256) Wb_sh[i] = Wb[i];
    __syncthreads();
    const int wave = threadIdx.x >> 6, lane = threadIdx.x & 63;
    const int sub = lane / SL;
    const int sl = lane % SL;
    const int c0 = sl * CPL;
    h2 w2h[8][CPL];
#pragma unroll
    for (int k2 = 0; k2 < 8; ++k2)
#pragma unroll
        for (int j = 0; j < CPL; ++j) {
            h2 t;
            t.x = (_Float16)Wae[(2 * k2) * H + c0 + j];
            t.y = (_Float16)Wae[(2 * k2 + 1) * H + c0 + j];
            w2h[k2][j] = t;
        }

    for (int v = blockIdx.x * NPB + wave * NPW + sub; v < N_NODES; v += gridDim.x * NPB) {
        float pd[CPL], acc[CPL];
        ld_f32<CPL>(&Pd[(size_t)v * H + c0], pd);
#pragma unroll
        for (int j = 0; j < CPL; ++j) acc[j] = 0.f;
        const int p0 = row_ptr[v], p1 = row_ptr[v + 1];
        const int deg = p1 - p0;

        auto edge = [&](uint4 ra, uint4 rb, const float ps[CPL]) {
            union { u32 u; h2 h; } cv;
            h2 ev[8];
            cv.u = ra.x; ev[0] = cv.h; cv.u = ra.y; ev[1] = cv.h;
            cv.u = ra.z; ev[2] = cv.h; cv.u = ra.w; ev[3] = cv.h;
            cv.u = rb.x; ev[4] = cv.h; cv.u = rb.y; ev[5] = cv.h;
            cv.u = rb.z; ev[6] = cv.h; cv.u = rb.w; ev[7] = cv.h;
            float z[CPL];
#pragma unroll
            for (int j = 0; j < CPL; ++j) z[j] = pd[j] + ps[j];
#pragma unroll
            for (int k2 = 0; k2 < 8; ++k2)
#pragma unroll
                for (int j = 0; j < CPL; ++j) z[j] = DOT2(ev[k2], w2h[k2][j], z[j]);
#pragma unroll
            for (int j = 0; j < CPL; ++j) acc[j] += fmaxf(z[j], 0.f);
        };

        int p = p0;
        for (; p + 1 < p1; p += 2) {
            int s0 = srcs[p], s1 = srcs[p + 1];
            const uint4* e0 = (const uint4*)(e16s + (size_t)p * 16);
            const uint4* e1 = (const uint4*)(e16s + (size_t)(p + 1) * 16);
            uint4 a0 = e0[0], a1 = e0[1];
            uint4 b0 = e1[0], b1 = e1[1];
            float ps0[CPL], ps1[CPL];
            ld_bf16<CPL>(&Ps[(size_t)s0 * H + c0], ps0);
            ld_bf16<CPL>(&Ps[(size_t)s1 * H + c0], ps1);
            edge(a0, a1, ps0);
            edge(b0, b1, ps1);
        }
        if (p < p1) {
            int s0 = srcs[p];
            const uint4* e0 = (const uint4*)(e16s + (size_t)p * 16);
            uint4 a0 = e0[0], a1 = e0[1];
            float ps0[CPL];
            ld_bf16<CPL>(&Ps[(size_t)s0 * H + c0], ps0);
            edge(a0, a1, ps0);
        }

        const float invd = (deg > 0) ? 1.f / (float)deg : 0.f;
        float m[CPL];
#pragma unroll
        for (int j = 0; j < CPL; ++j) m[j] = acc[j] * invd;
        const int co = (sl < Fo) ? sl : 0;
        float yv = 0.f;
#pragma unroll
        for (int k = 0; k < H; ++k)
            yv += __shfl(m[k % CPL], sub * SL + k / CPL) * Wb_sh[k * Fo + co];
        if (sl < Fo)
            y[(size_t)v * Fo + sl] = (deg > 0) ? (yv + bb[sl]) : 0.f;
    }
}

// ---------------- BN stats + normalize ----------------
template <int Fo>
__global__ __launch_bounds__(256) void stats2_k(const float* __restrict__ y, float* __restrict__ stats) {
    __shared__ float sh[2 * Fo];
    for (int i = threadIdx.x; i < 2 * Fo; i += 256) sh[i] = 0.f;
    __syncthreads();
    const int co = threadIdx.x % Fo;
    float s1 = 0.f, s2 = 0.f;
    const long long total = (long long)N_NODES * Fo;
    for (long long i = (long long)blockIdx.x * 256 + threadIdx.x; i < total; i += (long long)gridDim.x * 256) {
        float v = y[i];
        s1 += v; s2 += v * v;
    }
    atomicAdd(&sh[co], s1);
    atomicAdd(&sh[Fo + co], s2);
    __syncthreads();
    if (threadIdx.x < 2 * Fo) atomicAdd(&stats[threadIdx.x], sh[threadIdx.x]);
}

template <int Fo>
__global__ __launch_bounds__(256) void bnrelu_k(float* __restrict__ y,
        const float* __restrict__ stats, const float* __restrict__ g, const float* __restrict__ beta) {
    int idx = blockIdx.x * 256 + threadIdx.x;
    if (idx >= N_NODES * Fo) return;
    int co = idx % Fo;
    const float invN = 1.0f / (float)N_NODES;
    float mu = stats[co] * invN;
    float ex2 = stats[Fo + co] * invN;
    float var = fmaxf(ex2 - mu * mu, 0.f);
    float rs = rsqrtf(var + 1e-5f);
    y[idx] = fmaxf((y[idx] - mu) * rs * g[co] + beta[co], 0.f);
}

// ---------------- pooling & head ----------------
__global__ __launch_bounds__(256) void pool_k(const float* __restrict__ h,
        const int* __restrict__ batch, float* __restrict__ pool, int* __restrict__ gcnt) {
    int idx = blockIdx.x * 256 + threadIdx.x;
    if (idx >= N_NODES * 16) return;
    int v = idx >> 4, c = idx & 15;
    int b = batch[v];
    atomicAdd(&pool[b * 16 + c], h[idx]);
    if (c == 0) atomicAdd(&gcnt[b], 1);
}

__global__ __launch_bounds__(256) void out_k(const float* __restrict__ pool,
        const int* __restrict__ gcnt, const float* __restrict__ Wfc,
        const float* __restrict__ bfc, float* __restrict__ out) {
    int idx = blockIdx.x * 256 + threadIdx.x;
    if (idx >= NUM_GRAPHS * 12) return;
    int g = idx / 12, o = idx % 12;
    int cnt = gcnt[g];
    float inv = 1.0f / (float)(cnt > 0 ? cnt : 1);
    float acc = bfc[o];
#pragma unroll
    for (int k = 0; k < 16; ++k) acc += pool[g * 16 + k] * inv * Wfc[k * 12 + o];
    out[idx] = 1.0f / (1.0f + expf(-acc));
}

extern "C" void kernel_launch(void* const* d_in, const int* in_sizes, int n_in,
                              void* d_out, int out_size, void* d_ws, size_t ws_size,
                              hipStream_t stream) {
    const size_t N = N_NODES, E = N_EDGES, G = NUM_GRAPHS;
    const float* x = (const float*)d_in[0];
    const float* ea = (const float*)d_in[1];
    const int* ei = (const int*)d_in[2];
    const int* srcv = ei;
    const int* dstv = ei + E;
    const int* batch = (const int*)d_in[3];
    const float* Wn = (const float*)d_in[5];  const float* bn_ = (const float*)d_in[6];
    const float* We = (const float*)d_in[7];  const float* be_ = (const float*)d_in[8];
    const float* W1a = (const float*)d_in[9]; const float* b1a = (const float*)d_in[10];
    const float* W1b = (const float*)d_in[11]; const float* b1b = (const float*)d_in[12];
    const float* W2a = (const float*)d_in[13]; const float* b2a = (const float*)d_in[14];
    const float* W2b = (const float*)d_in[15]; const float* b2b = (const float*)d_in[16];
    const float* W3a = (const float*)d_in[17]; const float* b3a = (const float*)d_in[18];
    const float* W3b = (const float*)d_in[19]; const float* b3b = (const float*)d_in[20];
    const float* g1 = (const float*)d_in[21]; const float* be1 = (const float*)d_in[22];
    const float* g2 = (const float*)d_in[23]; const float* be2 = (const float*)d_in[24];
    const float* g3 = (const float*)d_in[25]; const float* be3 = (const float*)d_in[26];
    const float* Wfc = (const float*)d_in[27]; const float* bfc = (const float*)d_in[28];

    char* base = (char*)d_ws;
    size_t off = 0;
    auto take = [&](size_t bytes) { size_t o = off; off += (bytes + 255) & ~(size_t)255; return o; };
    int* hist = (int*)(base + take(N * 4));
    int* cursor = (int*)(base + take(N * 4));
    int* row_ptr = (int*)(base + take((N + 1) * 4));
    int* bsum = (int*)(base + take(256 * 4));
    int* boff = (int*)(base + take(256 * 4));
    int* sorted = (int*)(base + take(E * 4));
    int* srcs = (int*)(base + take(E * 4));
    float* hbuf = (float*)(base + take(N * 64 * 4));
    float* Pd = (float*)(base + take(N * 128 * 4));
    u16* Ps = (u16*)(base + take(N * 128 * 2));
    _Float16* e16s = (_Float16*)(base + take(E * 16 * 2));
    float* stats = (float*)(base + take(256 * 4));
    float* pool = (float*)(base + take(G * 16 * 4));
    int* gcnt = (int*)(base + take(G * 4));
    if (off > ws_size) {
        fprintf(stderr, "kernel_launch: ws too small: need %zu have %zu\n", off, ws_size);
        return;
    }

    const int NB = (N_NODES + 1023) / 1024;

    // CSR build (+ srcs in sorted order)
    hipMemsetAsync(hist, 0, N * 4, stream);
    hist_k<<<dim3((E + 255) / 256), dim3(256), 0, stream>>>(dstv, hist);
    scan_part_k<<<dim3(NB), dim3(256), 0, stream>>>(hist, cursor, bsum);
    scan_top_k<<<dim3(1), dim3(256), 0, stream>>>(bsum, boff, NB, &row_ptr[N_NODES]);
    scan_add_k<<<dim3((N + 255) / 256), dim3(256), 0, stream>>>(cursor, boff, row_ptr, cursor);
    scatter_k<<<dim3((E + 255) / 256), dim3(256), 0, stream>>>(srcv, dstv, cursor, sorted, srcs);

    // embeddings (e16 f16, CSR order)
    edge_emb_k<<<dim3((E * 16 + 255) / 256), dim3(256), 0, stream>>>(ea, We, be_, sorted, e16s);
    node_emb_k<<<dim3((N * 64 + 255) / 256), dim3(256), 0, stream>>>(x, Wn, bn_, hbuf);

    // conv1: F=64, H=128, Fo=64
    proj_k<64, 128><<<dim3((N * 128 + 255) / 256), dim3(256), 0, stream>>>(hbuf, W1a, b1a, Pd, Ps);
    conv_k<128, 64><<<dim3(3072), dim3(256), 0, stream>>>(row_ptr, srcs, e16s, Pd, Ps,
            W1a + 128 * 128, W1b, b1b, hbuf);
    hipMemsetAsync(stats, 0, 256 * 4, stream);
    stats2_k<64><<<dim3(512), dim3(256), 0, stream>>>(hbuf, stats);
    bnrelu_k<64><<<dim3((N * 64 + 255) / 256), dim3(256), 0, stream>>>(hbuf, stats, g1, be1);

    // conv2: F=64, H=64, Fo=32
    proj_k<64, 64><<<dim3((N * 64 + 255) / 256), dim3(256), 0, stream>>>(hbuf, W2a, b2a, Pd, Ps);
    conv_k<64, 32><<<dim3(3072), dim3(256), 0, stream>>>(row_ptr, srcs, e16s, Pd, Ps,
            W2a + 128 * 64, W2b, b2b, hbuf);
    hipMemsetAsync(stats, 0, 256 * 4, stream);
    stats2_k<32><<<dim3(512), dim3(256), 0, stream>>>(hbuf, stats);
    bnrelu_k<32><<<dim3((N * 32 + 255) / 256), dim3(256), 0, stream>>>(hbuf, stats, g2, be2);

    // conv3: F=32, H=32, Fo=16 (2 nodes/wave)
    proj_k<32, 32><<<dim3((N * 32 + 255) / 256), dim3(256), 0, stream>>>(hbuf, W3a, b3a, Pd, Ps);
    conv_k<32, 16><<<dim3(3072), dim3(256), 0, stream>>>(row_ptr, srcs, e16s, Pd, Ps,
            W3a + 64 * 32, W3b, b3b, hbuf);
    hipMemsetAsync(stats, 0, 256 * 4, stream);
    stats2_k<16><<<dim3(512), dim3(256), 0, stream>>>(hbuf, stats);
    bnrelu_k<16><<<dim3((N * 16 + 255) / 256), dim3(256), 0, stream>>>(hbuf, stats, g3, be3);

    // pool + head
    hipMemsetAsync(pool, 0, G * 16 * 4, stream);
    hipMemsetAsync(gcnt, 0, G * 4, stream);
    pool_k<<<dim3((N * 16 + 255) / 256), dim3(256), 0, stream>>>(hbuf, batch, pool, gcnt);
    out_k<<<dim3((G * 12 + 255) / 256), dim3(256), 0, stream>>>(pool, gcnt, Wfc, bfc, (float*)d_out);
}

// Round 11
// 1785.419 us; speedup vs baseline: 2.5457x; 1.2419x over previous
//
#include <hip/hip_runtime.h>
#include <hip/hip_bf16.h>
#include <cstdio>

// GCNTox21 — round 11. r10 post-mortem: __launch_bounds__(256,4) made the
// backend target 8 waves/SIMD -> 64 VGPRs -> SCRATCH SPILL in the edge loop
// (phantom 1.3GB WRITE_SIZE + 1.1GB extra FETCH on a 25MB-output kernel).
// Fix: plain __launch_bounds__(256); everything else identical to r10
// (dot2 edge loop, LDS Wb epilogue, Ps bf16 / Pd fp32 staging, CSR gather).

#define N_NODES 100000
#define N_EDGES 1600000
#define NUM_GRAPHS 4096

typedef unsigned short u16;
typedef unsigned int u32;
typedef _Float16 h2 __attribute__((ext_vector_type(2)));

#if defined(__has_builtin)
#if __has_builtin(__builtin_amdgcn_fdot2)
#define DOT2(a, b, c) __builtin_amdgcn_fdot2((a), (b), (c), false)
#endif
#endif
#ifndef DOT2
#define DOT2(a, b, c) ((c) + (float)(a).x * (float)(b).x + (float)(a).y * (float)(b).y)
#endif

__device__ __forceinline__ float b2f(u16 u) { union { u32 i; float f; } c; c.i = ((u32)u) << 16; return c.f; }
__device__ __forceinline__ float b2f_lo(u32 u) { union { u32 i; float f; } c; c.i = u << 16; return c.f; }
__device__ __forceinline__ float b2f_hi(u32 u) { union { u32 i; float f; } c; c.i = u & 0xffff0000u; return c.f; }
__device__ __forceinline__ u16 f2b(float f) {
    __hip_bfloat16 h = __float2bfloat16(f);
    return *reinterpret_cast<u16*>(&h);
}

template <int CPL>
__device__ __forceinline__ void ld_bf16(const u16* base, float out[CPL]) {
    if constexpr (CPL == 1) {
        out[0] = b2f(*base);
    } else {
        u32 v = *(const u32*)base;
        out[0] = b2f_lo(v); out[1] = b2f_hi(v);
    }
}
template <int CPL>
__device__ __forceinline__ void ld_f32(const float* base, float out[CPL]) {
    if constexpr (CPL == 1) {
        out[0] = *base;
    } else {
        float2 v = *(const float2*)base;
        out[0] = v.x; out[1] = v.y;
    }
}

// ---------------- CSR build ----------------
__global__ __launch_bounds__(256) void hist_k(const int* __restrict__ dst, int* __restrict__ hist) {
    int e = blockIdx.x * 256 + threadIdx.x;
    if (e < N_EDGES) atomicAdd(&hist[dst[e]], 1);
}

__global__ __launch_bounds__(256) void scan_part_k(const int* __restrict__ hist,
        int* __restrict__ excl, int* __restrict__ bsum) {
    __shared__ int sm[256];
    int t = threadIdx.x, b = blockIdx.x;
    int base = b * 1024 + t * 4;
    int v0 = (base + 0 < N_NODES) ? hist[base + 0] : 0;
    int v1 = (base + 1 < N_NODES) ? hist[base + 1] : 0;
    int v2 = (base + 2 < N_NODES) ? hist[base + 2] : 0;
    int v3 = (base + 3 < N_NODES) ? hist[base + 3] : 0;
    int tsum = v0 + v1 + v2 + v3;
    sm[t] = tsum;
    __syncthreads();
    for (int o = 1; o < 256; o <<= 1) {
        int x = (t >= o) ? sm[t - o] : 0;
        __syncthreads();
        sm[t] += x;
        __syncthreads();
    }
    int texcl = sm[t] - tsum;
    if (base + 0 < N_NODES) excl[base + 0] = texcl;
    if (base + 1 < N_NODES) excl[base + 1] = texcl + v0;
    if (base + 2 < N_NODES) excl[base + 2] = texcl + v0 + v1;
    if (base + 3 < N_NODES) excl[base + 3] = texcl + v0 + v1 + v2;
    if (t == 255) bsum[b] = sm[255];
}

__global__ __launch_bounds__(256) void scan_top_k(int* __restrict__ bsum, int* __restrict__ boff,
        int nb, int* __restrict__ row_ptr_last) {
    __shared__ int sm[256];
    int t = threadIdx.x;
    int v = (t < nb) ? bsum[t] : 0;
    sm[t] = v;
    __syncthreads();
    for (int o = 1; o < 256; o <<= 1) {
        int x = (t >= o) ? sm[t - o] : 0;
        __syncthreads();
        sm[t] += x;
        __syncthreads();
    }
    if (t < nb) boff[t] = sm[t] - v;
    if (t == 0) *row_ptr_last = sm[255];
}

__global__ __launch_bounds__(256) void scan_add_k(int* __restrict__ excl, const int* __restrict__ boff,
        int* __restrict__ row_ptr, int* __restrict__ cursor) {
    int i = blockIdx.x * 256 + threadIdx.x;
    if (i >= N_NODES) return;
    int s = excl[i] + boff[i >> 10];
    row_ptr[i] = s;
    cursor[i] = s;
}

__global__ __launch_bounds__(256) void scatter_k(const int* __restrict__ src, const int* __restrict__ dst,
        int* __restrict__ cursor, int* __restrict__ sorted_eid, int* __restrict__ srcs) {
    int e = blockIdx.x * 256 + threadIdx.x;
    if (e < N_EDGES) {
        int p = atomicAdd(&cursor[dst[e]], 1);
        sorted_eid[p] = e;
        srcs[p] = src[e];
    }
}

// ---------------- embeddings ----------------
__global__ __launch_bounds__(256) void edge_emb_k(const float* __restrict__ ea,
        const float* __restrict__ We, const float* __restrict__ be,
        const int* __restrict__ sorted_eid, _Float16* __restrict__ e16s) {
    int idx = blockIdx.x * 256 + threadIdx.x;
    if (idx >= N_EDGES * 16) return;
    int p = idx >> 4, k = idx & 15;
    int e = sorted_eid[p];
    float acc = be[k];
#pragma unroll
    for (int j = 0; j < 8; ++j) acc += ea[(size_t)e * 8 + j] * We[j * 16 + k];
    e16s[idx] = (_Float16)fmaxf(acc, 0.f);
}

__global__ __launch_bounds__(256) void node_emb_k(const float* __restrict__ x,
        const float* __restrict__ Wn, const float* __restrict__ bn_, float* __restrict__ h) {
    int idx = blockIdx.x * 256 + threadIdx.x;
    if (idx >= N_NODES * 64) return;
    int v = idx >> 6, c = idx & 63;
    float acc = bn_[c];
    for (int k = 0; k < 32; ++k) acc += x[(size_t)v * 32 + k] * Wn[(size_t)k * 64 + c];
    h[idx] = fmaxf(acc, 0.f);
}

// ---------------- projections: Pd fp32, Ps bf16 ----------------
template <int F, int H>
__global__ __launch_bounds__(256) void proj_k(const float* __restrict__ h,
        const float* __restrict__ Wa, const float* __restrict__ ba,
        float* __restrict__ Pd, u16* __restrict__ Ps) {
    int idx = blockIdx.x * 256 + threadIdx.x;
    if (idx >= N_NODES * H) return;
    int v = idx / H, c = idx % H;
    float ad = ba[c], as = 0.f;
    const float* hr = h + (size_t)v * F;
    for (int k = 0; k < F; ++k) {
        float hk = hr[k];
        ad += hk * Wa[(size_t)k * H + c];
        as += hk * Wa[(size_t)(F + k) * H + c];
    }
    Pd[idx] = ad;
    Ps[idx] = f2b(as);
}

// ---------------- fused conv: CSR gather + mean + Wb mat-vec (LDS Wb) ------
template <int H, int Fo>
__global__ __launch_bounds__(256) void conv_k(      // NOTE: no min-waves hint (r10 spilled)
        const int* __restrict__ row_ptr, const int* __restrict__ srcs,
        const _Float16* __restrict__ e16s,
        const float* __restrict__ Pd, const u16* __restrict__ Ps,
        const float* __restrict__ Wae, const float* __restrict__ Wb,
        const float* __restrict__ bb, float* __restrict__ y) {
    constexpr int SL = (H >= 64) ? 64 : 32;   // lanes per node
    constexpr int NPW = 64 / SL;              // nodes per wave
    constexpr int CPL = H / SL;               // channels per lane
    constexpr int NPB = 4 * NPW;              // nodes per block per iter
    __shared__ float Wb_sh[H * Fo];
    for (int i = threadIdx.x; i < H * Fo; i += 256) Wb_sh[i] = Wb[i];
    __syncthreads();
    const int wave = threadIdx.x >> 6, lane = threadIdx.x & 63;
    const int sub = lane / SL;
    const int sl = lane % SL;
    const int c0 = sl * CPL;
    h2 w2h[8][CPL];
#pragma unroll
    for (int k2 = 0; k2 < 8; ++k2)
#pragma unroll
        for (int j = 0; j < CPL; ++j) {
            h2 t;
            t.x = (_Float16)Wae[(2 * k2) * H + c0 + j];
            t.y = (_Float16)Wae[(2 * k2 + 1) * H + c0 + j];
            w2h[k2][j] = t;
        }

    for (int v = blockIdx.x * NPB + wave * NPW + sub; v < N_NODES; v += gridDim.x * NPB) {
        float pd[CPL], acc[CPL];
        ld_f32<CPL>(&Pd[(size_t)v * H + c0], pd);
#pragma unroll
        for (int j = 0; j < CPL; ++j) acc[j] = 0.f;
        const int p0 = row_ptr[v], p1 = row_ptr[v + 1];
        const int deg = p1 - p0;

        auto edge = [&](uint4 ra, uint4 rb, const float ps[CPL]) {
            union { u32 u; h2 h; } cv;
            h2 ev[8];
            cv.u = ra.x; ev[0] = cv.h; cv.u = ra.y; ev[1] = cv.h;
            cv.u = ra.z; ev[2] = cv.h; cv.u = ra.w; ev[3] = cv.h;
            cv.u = rb.x; ev[4] = cv.h; cv.u = rb.y; ev[5] = cv.h;
            cv.u = rb.z; ev[6] = cv.h; cv.u = rb.w; ev[7] = cv.h;
            float z[CPL];
#pragma unroll
            for (int j = 0; j < CPL; ++j) z[j] = pd[j] + ps[j];
#pragma unroll
            for (int k2 = 0; k2 < 8; ++k2)
#pragma unroll
                for (int j = 0; j < CPL; ++j) z[j] = DOT2(ev[k2], w2h[k2][j], z[j]);
#pragma unroll
            for (int j = 0; j < CPL; ++j) acc[j] += fmaxf(z[j], 0.f);
        };

        int p = p0;
        for (; p + 1 < p1; p += 2) {
            int s0 = srcs[p], s1 = srcs[p + 1];
            const uint4* e0 = (const uint4*)(e16s + (size_t)p * 16);
            const uint4* e1 = (const uint4*)(e16s + (size_t)(p + 1) * 16);
            uint4 a0 = e0[0], a1 = e0[1];
            uint4 b0 = e1[0], b1 = e1[1];
            float ps0[CPL], ps1[CPL];
            ld_bf16<CPL>(&Ps[(size_t)s0 * H + c0], ps0);
            ld_bf16<CPL>(&Ps[(size_t)s1 * H + c0], ps1);
            edge(a0, a1, ps0);
            edge(b0, b1, ps1);
        }
        if (p < p1) {
            int s0 = srcs[p];
            const uint4* e0 = (const uint4*)(e16s + (size_t)p * 16);
            uint4 a0 = e0[0], a1 = e0[1];
            float ps0[CPL];
            ld_bf16<CPL>(&Ps[(size_t)s0 * H + c0], ps0);
            edge(a0, a1, ps0);
        }

        const float invd = (deg > 0) ? 1.f / (float)deg : 0.f;
        float m[CPL];
#pragma unroll
        for (int j = 0; j < CPL; ++j) m[j] = acc[j] * invd;
        const int co = (sl < Fo) ? sl : 0;
        float yv = 0.f;
#pragma unroll
        for (int k = 0; k < H; ++k)
            yv += __shfl(m[k % CPL], sub * SL + k / CPL) * Wb_sh[k * Fo + co];
        if (sl < Fo)
            y[(size_t)v * Fo + sl] = (deg > 0) ? (yv + bb[sl]) : 0.f;
    }
}

// ---------------- BN stats + normalize ----------------
template <int Fo>
__global__ __launch_bounds__(256) void stats2_k(const float* __restrict__ y, float* __restrict__ stats) {
    __shared__ float sh[2 * Fo];
    for (int i = threadIdx.x; i < 2 * Fo; i += 256) sh[i] = 0.f;
    __syncthreads();
    const int co = threadIdx.x % Fo;
    float s1 = 0.f, s2 = 0.f;
    const long long total = (long long)N_NODES * Fo;
    for (long long i = (long long)blockIdx.x * 256 + threadIdx.x; i < total; i += (long long)gridDim.x * 256) {
        float v = y[i];
        s1 += v; s2 += v * v;
    }
    atomicAdd(&sh[co], s1);
    atomicAdd(&sh[Fo + co], s2);
    __syncthreads();
    if (threadIdx.x < 2 * Fo) atomicAdd(&stats[threadIdx.x], sh[threadIdx.x]);
}

template <int Fo>
__global__ __launch_bounds__(256) void bnrelu_k(float* __restrict__ y,
        const float* __restrict__ stats, const float* __restrict__ g, const float* __restrict__ beta) {
    int idx = blockIdx.x * 256 + threadIdx.x;
    if (idx >= N_NODES * Fo) return;
    int co = idx % Fo;
    const float invN = 1.0f / (float)N_NODES;
    float mu = stats[co] * invN;
    float ex2 = stats[Fo + co] * invN;
    float var = fmaxf(ex2 - mu * mu, 0.f);
    float rs = rsqrtf(var + 1e-5f);
    y[idx] = fmaxf((y[idx] - mu) * rs * g[co] + beta[co], 0.f);
}

// ---------------- pooling & head ----------------
__global__ __launch_bounds__(256) void pool_k(const float* __restrict__ h,
        const int* __restrict__ batch, float* __restrict__ pool, int* __restrict__ gcnt) {
    int idx = blockIdx.x * 256 + threadIdx.x;
    if (idx >= N_NODES * 16) return;
    int v = idx >> 4, c = idx & 15;
    int b = batch[v];
    atomicAdd(&pool[b * 16 + c], h[idx]);
    if (c == 0) atomicAdd(&gcnt[b], 1);
}

__global__ __launch_bounds__(256) void out_k(const float* __restrict__ pool,
        const int* __restrict__ gcnt, const float* __restrict__ Wfc,
        const float* __restrict__ bfc, float* __restrict__ out) {
    int idx = blockIdx.x * 256 + threadIdx.x;
    if (idx >= NUM_GRAPHS * 12) return;
    int g = idx / 12, o = idx % 12;
    int cnt = gcnt[g];
    float inv = 1.0f / (float)(cnt > 0 ? cnt : 1);
    float acc = bfc[o];
#pragma unroll
    for (int k = 0; k < 16; ++k) acc += pool[g * 16 + k] * inv * Wfc[k * 12 + o];
    out[idx] = 1.0f / (1.0f + expf(-acc));
}

extern "C" void kernel_launch(void* const* d_in, const int* in_sizes, int n_in,
                              void* d_out, int out_size, void* d_ws, size_t ws_size,
                              hipStream_t stream) {
    const size_t N = N_NODES, E = N_EDGES, G = NUM_GRAPHS;
    const float* x = (const float*)d_in[0];
    const float* ea = (const float*)d_in[1];
    const int* ei = (const int*)d_in[2];
    const int* srcv = ei;
    const int* dstv = ei + E;
    const int* batch = (const int*)d_in[3];
    const float* Wn = (const float*)d_in[5];  const float* bn_ = (const float*)d_in[6];
    const float* We = (const float*)d_in[7];  const float* be_ = (const float*)d_in[8];
    const float* W1a = (const float*)d_in[9]; const float* b1a = (const float*)d_in[10];
    const float* W1b = (const float*)d_in[11]; const float* b1b = (const float*)d_in[12];
    const float* W2a = (const float*)d_in[13]; const float* b2a = (const float*)d_in[14];
    const float* W2b = (const float*)d_in[15]; const float* b2b = (const float*)d_in[16];
    const float* W3a = (const float*)d_in[17]; const float* b3a = (const float*)d_in[18];
    const float* W3b = (const float*)d_in[19]; const float* b3b = (const float*)d_in[20];
    const float* g1 = (const float*)d_in[21]; const float* be1 = (const float*)d_in[22];
    const float* g2 = (const float*)d_in[23]; const float* be2 = (const float*)d_in[24];
    const float* g3 = (const float*)d_in[25]; const float* be3 = (const float*)d_in[26];
    const float* Wfc = (const float*)d_in[27]; const float* bfc = (const float*)d_in[28];

    char* base = (char*)d_ws;
    size_t off = 0;
    auto take = [&](size_t bytes) { size_t o = off; off += (bytes + 255) & ~(size_t)255; return o; };
    int* hist = (int*)(base + take(N * 4));
    int* cursor = (int*)(base + take(N * 4));
    int* row_ptr = (int*)(base + take((N + 1) * 4));
    int* bsum = (int*)(base + take(256 * 4));
    int* boff = (int*)(base + take(256 * 4));
    int* sorted = (int*)(base + take(E * 4));
    int* srcs = (int*)(base + take(E * 4));
    float* hbuf = (float*)(base + take(N * 64 * 4));
    float* Pd = (float*)(base + take(N * 128 * 4));
    u16* Ps = (u16*)(base + take(N * 128 * 2));
    _Float16* e16s = (_Float16*)(base + take(E * 16 * 2));
    float* stats = (float*)(base + take(256 * 4));
    float* pool = (float*)(base + take(G * 16 * 4));
    int* gcnt = (int*)(base + take(G * 4));
    if (off > ws_size) {
        fprintf(stderr, "kernel_launch: ws too small: need %zu have %zu\n", off, ws_size);
        return;
    }

    const int NB = (N_NODES + 1023) / 1024;

    // CSR build (+ srcs in sorted order)
    hipMemsetAsync(hist, 0, N * 4, stream);
    hist_k<<<dim3((E + 255) / 256), dim3(256), 0, stream>>>(dstv, hist);
    scan_part_k<<<dim3(NB), dim3(256), 0, stream>>>(hist, cursor, bsum);
    scan_top_k<<<dim3(1), dim3(256), 0, stream>>>(bsum, boff, NB, &row_ptr[N_NODES]);
    scan_add_k<<<dim3((N + 255) / 256), dim3(256), 0, stream>>>(cursor, boff, row_ptr, cursor);
    scatter_k<<<dim3((E + 255) / 256), dim3(256), 0, stream>>>(srcv, dstv, cursor, sorted, srcs);

    // embeddings (e16 f16, CSR order)
    edge_emb_k<<<dim3((E * 16 + 255) / 256), dim3(256), 0, stream>>>(ea, We, be_, sorted, e16s);
    node_emb_k<<<dim3((N * 64 + 255) / 256), dim3(256), 0, stream>>>(x, Wn, bn_, hbuf);

    // conv1: F=64, H=128, Fo=64
    proj_k<64, 128><<<dim3((N * 128 + 255) / 256), dim3(256), 0, stream>>>(hbuf, W1a, b1a, Pd, Ps);
    conv_k<128, 64><<<dim3(3072), dim3(256), 0, stream>>>(row_ptr, srcs, e16s, Pd, Ps,
            W1a + 128 * 128, W1b, b1b, hbuf);
    hipMemsetAsync(stats, 0, 256 * 4, stream);
    stats2_k<64><<<dim3(512), dim3(256), 0, stream>>>(hbuf, stats);
    bnrelu_k<64><<<dim3((N * 64 + 255) / 256), dim3(256), 0, stream>>>(hbuf, stats, g1, be1);

    // conv2: F=64, H=64, Fo=32
    proj_k<64, 64><<<dim3((N * 64 + 255) / 256), dim3(256), 0, stream>>>(hbuf, W2a, b2a, Pd, Ps);
    conv_k<64, 32><<<dim3(3072), dim3(256), 0, stream>>>(row_ptr, srcs, e16s, Pd, Ps,
            W2a + 128 * 64, W2b, b2b, hbuf);
    hipMemsetAsync(stats, 0, 256 * 4, stream);
    stats2_k<32><<<dim3(512), dim3(256), 0, stream>>>(hbuf, stats);
    bnrelu_k<32><<<dim3((N * 32 + 255) / 256), dim3(256), 0, stream>>>(hbuf, stats, g2, be2);

    // conv3: F=32, H=32, Fo=16 (2 nodes/wave)
    proj_k<32, 32><<<dim3((N * 32 + 255) / 256), dim3(256), 0, stream>>>(hbuf, W3a, b3a, Pd, Ps);
    conv_k<32, 16><<<dim3(3072), dim3(256), 0, stream>>>(row_ptr, srcs, e16s, Pd, Ps,
            W3a + 64 * 32, W3b, b3b, hbuf);
    hipMemsetAsync(stats, 0, 256 * 4, stream);
    stats2_k<16><<<dim3(512), dim3(256), 0, stream>>>(hbuf, stats);
    bnrelu_k<16><<<dim3((N * 16 + 255) / 256), dim3(256), 0, stream>>>(hbuf, stats, g3, be3);

    // pool + head
    hipMemsetAsync(pool, 0, G * 16 * 4, stream);
    hipMemsetAsync(gcnt, 0, G * 4, stream);
    pool_k<<<dim3((N * 16 + 255) / 256), dim3(256), 0, stream>>>(hbuf, batch, pool, gcnt);
    out_k<<<dim3((G * 12 + 255) / 256), dim3(256), 0, stream>>>(pool, gcnt, Wfc, bfc, (float*)d_out);
}